// Round 1
// baseline (473.570 us; speedup 1.0000x reference)
//
#include <hip/hip_runtime.h>

// HopAttentionLayer: B=256, T=64, N=2048, D=128, fp32.
// attention[b,n] = softmax_n( T * dot(context[b,n,:], W[D:2D]) )
//   (tgt_term[b] and T*b0 are constant over n -> cancel in softmax)
// out[b,n,d] = attention[b,n] * context[b,n,d]
//
// R3: FULL FUSION. One 1024-thread block per batch (256 blocks = 1/CU).
//  - scores live in LDS only (no 2 MiB HBM round-trip, no extra dispatches)
//  - phase-3 re-read of ctx[b] (1 MiB) happens immediately after phase 1
//    touched it -> L2/L3-resident, instead of after a full 256 MiB stream
//  - nt loads/stores in phase 3: output stream must not evict cached ctx

#define B_DIM 256
#define N_DIM 2048
#define D_DIM 128
#define DVEC  (D_DIM / 4)      // 32 float4 per row
#define NTHR  1024             // 16 waves
#define T_SCALE 64.0f

typedef float f4v __attribute__((ext_vector_type(4)));

__global__ __launch_bounds__(NTHR)
void k_fused(const float* __restrict__ ctx, const float* __restrict__ W,
             float* __restrict__ out) {
    const int tid  = threadIdx.x;
    const int wave = tid >> 6;          // 0..15
    const int lane = tid & 63;
    const int sub  = lane & 31;         // lane within half-wave
    const int half = lane >> 5;
    const int b    = blockIdx.x;

    __shared__ float sm[N_DIM];         // scores -> probabilities (8 KiB)
    __shared__ float red[16];

    const size_t cbase = (size_t)b * ((size_t)N_DIM * DVEC);
    const f4v* __restrict__ c4 = (const f4v*)ctx + cbase;
    f4v*       __restrict__ o4 = (f4v*)out + cbase;

    const f4v wc = ((const f4v*)(W + D_DIM))[sub];   // Wc fragment, per lane

    // ---- Phase 1: sm[n] = T * dot(ctx[b,n,:], Wc) ----
    // half-wave (32 lanes) per row: one float4/lane, 5-step shfl reduce.
    // wave reads rows {it*32 + wave*2, +1} = 1 KiB contiguous.
    #pragma unroll 4
    for (int it = 0; it < N_DIM / 32; ++it) {
        const int n = it * 32 + wave * 2 + half;
        const f4v v = c4[(size_t)n * DVEC + sub];
        float p = v.x * wc.x + v.y * wc.y + v.z * wc.z + v.w * wc.w;
        #pragma unroll
        for (int m = 1; m < 32; m <<= 1) p += __shfl_xor(p, m, 64);  // in-half
        if (sub == 0) sm[n] = T_SCALE * p;
    }
    __syncthreads();

    // ---- Phase 2: softmax over sm[0..2047], entirely on-chip ----
    const float a0 = sm[tid];
    const float a1 = sm[tid + NTHR];
    float mx = fmaxf(a0, a1);
    #pragma unroll
    for (int m = 1; m < 64; m <<= 1) mx = fmaxf(mx, __shfl_xor(mx, m, 64));
    if (lane == 0) red[wave] = mx;
    __syncthreads();
    float gmax = red[0];
    #pragma unroll
    for (int i = 1; i < 16; ++i) gmax = fmaxf(gmax, red[i]);

    const float e0 = __expf(a0 - gmax);
    const float e1 = __expf(a1 - gmax);
    float s = e0 + e1;
    #pragma unroll
    for (int m = 1; m < 64; m <<= 1) s += __shfl_xor(s, m, 64);
    __syncthreads();                    // all done reading red (max)
    if (lane == 0) red[wave] = s;
    __syncthreads();
    float tot = red[0];
    #pragma unroll
    for (int i = 1; i < 16; ++i) tot += red[i];
    const float inv = 1.0f / tot;

    sm[tid]        = e0 * inv;
    sm[tid + NTHR] = e1 * inv;
    __syncthreads();

    // ---- Phase 3: out[n,:] = sm[n] * ctx[n,:] ----
    // Immediately re-reads the 1 MiB this block just streamed (L2/L3-hot).
    // Wave reads 64 consecutive float4 = 1 KiB; sm broadcast (2 rows/wave).
    #pragma unroll 4
    for (int i = 0; i < (N_DIM * DVEC) / NTHR; ++i) {   // 64 iters
        const int f = i * NTHR + tid;
        const float w = sm[f >> 5];
        f4v v = __builtin_nontemporal_load(&c4[f]);
        v *= w;
        __builtin_nontemporal_store(v, &o4[f]);
    }
}

extern "C" void kernel_launch(void* const* d_in, const int* in_sizes, int n_in,
                              void* d_out, int out_size, void* d_ws, size_t ws_size,
                              hipStream_t stream) {
    (void)in_sizes; (void)n_in; (void)out_size; (void)d_ws; (void)ws_size;
    // d_in[0] = targetsentence_emb (unused: cancels in softmax)
    // d_in[1] = context_emb, d_in[2] = W, d_in[3] = b (unused: cancels)
    const float* ctx = (const float*)d_in[1];
    const float* W   = (const float*)d_in[2];
    float* out       = (float*)d_out;

    hipLaunchKernelGGL(k_fused, dim3(B_DIM), dim3(NTHR), 0, stream,
                       ctx, W, out);
}